// Round 4
// baseline (596.327 us; speedup 1.0000x reference)
//
#include <hip/hip_runtime.h>
#include <cstdint>
#include <math.h>

#define IMH 2048
#define IMW 2048
#define NB 4
#define NPIX (NB*IMH*IMW)        // 16777216
#define MEDRANK ((NPIX-1)/2)     // 8388607
#define ALPHA 0.05f

// front tile: 64 wide x 24 tall
#define TW 64
#define TH 24
#define XROWS (TH+10)   // 34
#define XSTR 84
#define HROWS (TH+8)    // 32
#define HSTR 68
#define GX 32
#define GY 86           // ceil(2048/24)
#define GTOT (GX*GY*NB) // 11008
#define H8REP 64        // global h8 replicas

__device__ __forceinline__ uint32_t fkey(float f){
  uint32_t u = __float_as_uint(f);
  return (u & 0x80000000u) ? ~u : (u | 0x80000000u);
}
__device__ __forceinline__ uint32_t aload(const uint32_t* p){
  return __hip_atomic_load(p, __ATOMIC_RELAXED, __HIP_MEMORY_SCOPE_AGENT);
}
__device__ __forceinline__ float ldz(const float* __restrict__ p, int r, int c){
  return (r >= 0 && r < IMH && c >= 0 && c < IMW) ? p[(size_t)r*IMW + c] : 0.f;
}

// ---------------------------------------------------------------------------
// Fused Sobel(separable) -> products -> 9x9 Gaussian -> Harris R
//   + per-block 256-bin histogram of fkey(R)>>24 (u16-packed, x4 replicas)
//   + tail-block 8-bit median select (writes state[0..1]).
// LDS: xs 11424 + hs 26112 + h16 2048 = 39584 B -> 4 blocks/CU (LDS-limited).
// NO VGPR-capping launch_bounds: R3's (256,4) forced 64 VGPRs -> 330MB scratch
// spill traffic. Let the compiler pick (~110 expected, <=128 keeps 4 blocks).
// ---------------------------------------------------------------------------
__global__ __launch_bounds__(256) void harris_front(
    const float* __restrict__ x, const float* __restrict__ gauss_w,
    float* __restrict__ R, uint32_t* __restrict__ h8g,
    uint32_t* __restrict__ state, uint32_t* __restrict__ fctr)
{
  __shared__ float xs[XROWS][XSTR];
  __shared__ float hs[3][HROWS][HSTR];
  __shared__ uint32_t h16[128*4];   // bin pair b=word, low16=bin 2w, high16=2w+1; 4 copies
  __shared__ int lastFlag;

  const int tid = threadIdx.x;
  const int C0 = blockIdx.x * TW;
  const int R0 = blockIdx.y * TH;
  const int n  = blockIdx.z;
  const int bid = blockIdx.x + GX*(blockIdx.y + GY*blockIdx.z);
  const float* xb = x + (size_t)n * (size_t)(IMH*IMW);

  if (tid < 128){ h16[tid*4+0]=0; h16[tid*4+1]=0; h16[tid*4+2]=0; h16[tid*4+3]=0; }

  float ga[9];
  {
    float a4 = sqrtf(gauss_w[4*9+4]);
#pragma unroll
    for (int i = 0; i < 9; i++) ga[i] = gauss_w[4*9+i] / a4;
  }

  // ---- load x tile: rows R0-5..R0+28 (34), cols C0-8..C0+71 (80) ----
  for (int u = tid; u < XROWS*20; u += 256){
    int r = u / 20, c4 = u % 20;
    int gr = R0 - 5 + r;
    int gc = C0 - 8 + c4*4;
    float4 v;
    if (gr >= 0 && gr < IMH && gc >= 0 && gc + 3 < IMW){
      v = *reinterpret_cast<const float4*>(&xb[(size_t)gr*IMW + gc]);
    } else {
      v.x = ldz(xb, gr, gc+0); v.y = ldz(xb, gr, gc+1);
      v.z = ldz(xb, gr, gc+2); v.w = ldz(xb, gr, gc+3);
    }
    *reinterpret_cast<float4*>(&xs[r][c4*4]) = v;
  }
  __syncthreads();

  // ---- horizontal: Sobel + products + h-gauss, 1 item/thread ----
  {
    const int hr = tid >> 3;            // hs row 0..31
    const int oc = (tid & 7) * 8;       // output col group (8 cols)
    const int gr = R0 - 4 + hr;         // product row
    const bool rowv = ((unsigned)gr < (unsigned)IMH);

    float ix[16], iy[16];
    {
      // window: xs cols oc..oc+23 ; sv/dv die after ix/iy are built
      float sv[24], dv[24];
#pragma unroll
      for (int m = 0; m < 6; m++){
        float4 a = *reinterpret_cast<const float4*>(&xs[hr  ][oc + m*4]);
        float4 b = *reinterpret_cast<const float4*>(&xs[hr+1][oc + m*4]);
        float4 c = *reinterpret_cast<const float4*>(&xs[hr+2][oc + m*4]);
        sv[m*4+0] = fmaf(2.f, b.x, a.x + c.x);  dv[m*4+0] = c.x - a.x;
        sv[m*4+1] = fmaf(2.f, b.y, a.y + c.y);  dv[m*4+1] = c.y - a.y;
        sv[m*4+2] = fmaf(2.f, b.z, a.z + c.z);  dv[m*4+2] = c.z - a.z;
        sv[m*4+3] = fmaf(2.f, b.w, a.w + c.w);  dv[m*4+3] = c.w - a.w;
      }
#pragma unroll
      for (int j = 0; j < 16; j++){
        float vx = sv[j+5] - sv[j+3];
        float vy = dv[j+3] + fmaf(2.f, dv[j+4], dv[j+5]);
        int gc = C0 + oc - 4 + j;
        bool vld = rowv && ((unsigned)gc < (unsigned)IMW);
        ix[j] = vld ? vx : 0.f;
        iy[j] = vld ? vy : 0.f;
      }
    }
#pragma unroll
    for (int p = 0; p < 3; p++){
      float pr[16];
#pragma unroll
      for (int j = 0; j < 16; j++)
        pr[j] = (p == 0) ? ix[j]*ix[j] : (p == 1) ? iy[j]*iy[j] : ix[j]*iy[j];
      float o[8];
#pragma unroll
      for (int t2 = 0; t2 < 8; t2++){
        float s = 0.f;
#pragma unroll
        for (int k = 0; k < 9; k++) s = fmaf(ga[k], pr[t2+k], s);
        o[t2] = s;
      }
      *reinterpret_cast<float4*>(&hs[p][hr][oc])   = make_float4(o[0],o[1],o[2],o[3]);
      *reinterpret_cast<float4*>(&hs[p][hr][oc+4]) = make_float4(o[4],o[5],o[6],o[7]);
    }
  }
  __syncthreads();

  // ---- vertical gauss + Harris + R write + LDS histogram ----
  if (tid < 192){
    const int c4o = tid & 15;
    const int r0o = (tid >> 4) * 2;     // 0..22
    float4 sA[3], sB[3];
#pragma unroll
    for (int p = 0; p < 3; p++){
      float4 a0 = make_float4(0,0,0,0), a1 = make_float4(0,0,0,0);
#pragma unroll
      for (int k = 0; k < 10; k++){
        float4 hv = *reinterpret_cast<const float4*>(&hs[p][r0o+k][c4o*4]);
        if (k < 9){
          a0.x = fmaf(ga[k], hv.x, a0.x); a0.y = fmaf(ga[k], hv.y, a0.y);
          a0.z = fmaf(ga[k], hv.z, a0.z); a0.w = fmaf(ga[k], hv.w, a0.w);
        }
        if (k >= 1){
          a1.x = fmaf(ga[k-1], hv.x, a1.x); a1.y = fmaf(ga[k-1], hv.y, a1.y);
          a1.z = fmaf(ga[k-1], hv.z, a1.z); a1.w = fmaf(ga[k-1], hv.w, a1.w);
        }
      }
      sA[p] = a0; sB[p] = a1;
    }
    float* Rb = R + (size_t)n * (size_t)(IMH*IMW);
    float4 o0, o1;
    float s0, s1, s2, det, tr;
    s0=sA[0].x; s1=sA[1].x; s2=sA[2].x; det=s0*s1-s2*s2; tr=s0+s1; o0.x=det-ALPHA*tr*tr;
    s0=sA[0].y; s1=sA[1].y; s2=sA[2].y; det=s0*s1-s2*s2; tr=s0+s1; o0.y=det-ALPHA*tr*tr;
    s0=sA[0].z; s1=sA[1].z; s2=sA[2].z; det=s0*s1-s2*s2; tr=s0+s1; o0.z=det-ALPHA*tr*tr;
    s0=sA[0].w; s1=sA[1].w; s2=sA[2].w; det=s0*s1-s2*s2; tr=s0+s1; o0.w=det-ALPHA*tr*tr;
    s0=sB[0].x; s1=sB[1].x; s2=sB[2].x; det=s0*s1-s2*s2; tr=s0+s1; o1.x=det-ALPHA*tr*tr;
    s0=sB[0].y; s1=sB[1].y; s2=sB[2].y; det=s0*s1-s2*s2; tr=s0+s1; o1.y=det-ALPHA*tr*tr;
    s0=sB[0].z; s1=sB[1].z; s2=sB[2].z; det=s0*s1-s2*s2; tr=s0+s1; o1.z=det-ALPHA*tr*tr;
    s0=sB[0].w; s1=sB[1].w; s2=sB[2].w; det=s0*s1-s2*s2; tr=s0+s1; o1.w=det-ALPHA*tr*tr;

    const int orow = R0 + r0o;
    const int ocol = C0 + c4o*4;
    const uint32_t copy = (uint32_t)(tid & 3);
    if (orow < IMH){
      *reinterpret_cast<float4*>(&Rb[(size_t)orow*IMW + ocol]) = o0;
      uint32_t b;
      b = fkey(o0.x) >> 24; atomicAdd(&h16[(b>>1)*4+copy], (b&1) ? 65536u : 1u);
      b = fkey(o0.y) >> 24; atomicAdd(&h16[(b>>1)*4+copy], (b&1) ? 65536u : 1u);
      b = fkey(o0.z) >> 24; atomicAdd(&h16[(b>>1)*4+copy], (b&1) ? 65536u : 1u);
      b = fkey(o0.w) >> 24; atomicAdd(&h16[(b>>1)*4+copy], (b&1) ? 65536u : 1u);
    }
    if (orow + 1 < IMH){
      *reinterpret_cast<float4*>(&Rb[(size_t)(orow+1)*IMW + ocol]) = o1;
      uint32_t b;
      b = fkey(o1.x) >> 24; atomicAdd(&h16[(b>>1)*4+copy], (b&1) ? 65536u : 1u);
      b = fkey(o1.y) >> 24; atomicAdd(&h16[(b>>1)*4+copy], (b&1) ? 65536u : 1u);
      b = fkey(o1.z) >> 24; atomicAdd(&h16[(b>>1)*4+copy], (b&1) ? 65536u : 1u);
      b = fkey(o1.w) >> 24; atomicAdd(&h16[(b>>1)*4+copy], (b&1) ? 65536u : 1u);
    }
  }
  __syncthreads();

  // ---- merge block hist into replicated global hist ----
  {
    const int t = tid;
    const int w = t >> 1, sh = (t & 1) * 16;
    uint32_t s = ((h16[w*4+0] >> sh) & 0xffffu) + ((h16[w*4+1] >> sh) & 0xffffu)
               + ((h16[w*4+2] >> sh) & 0xffffu) + ((h16[w*4+3] >> sh) & 0xffffu);
    if (s) atomicAdd(&h8g[(bid & (H8REP-1))*256 + t], s);
  }
  __syncthreads();
  if (tid == 0){
    __threadfence();
    lastFlag = (atomicAdd(fctr, 1u) == (uint32_t)GTOT - 1u);
  }
  __syncthreads();
  if (!lastFlag) return;
  __threadfence();

  // ---- tail: 8-bit median select ----
  uint32_t* sc = (uint32_t*)&xs[0][0];
  const int t = tid;
  uint32_t cnt = 0;
  for (int c = 0; c < H8REP; c++) cnt += aload(&h8g[c*256 + t]);
  sc[t] = cnt;
  __syncthreads();
  for (int off = 1; off < 256; off <<= 1){
    uint32_t v = (t >= off) ? sc[t-off] : 0u;
    __syncthreads();
    sc[t] += v;
    __syncthreads();
  }
  uint32_t excl = sc[t] - cnt;
  if ((uint32_t)MEDRANK >= excl && (uint32_t)MEDRANK < excl + cnt){
    state[0] = (uint32_t)t;
    state[1] = (uint32_t)MEDRANK - excl;
  }
}

// ---------------------------------------------------------------------------
// 12-bit refinement passes with tail-block select.
// ---------------------------------------------------------------------------
__global__ __launch_bounds__(256) void harris_hist12(
    const float4* __restrict__ R4, uint32_t* __restrict__ h,
    uint32_t* __restrict__ state, uint32_t* __restrict__ ctr, int phase)
{
  __shared__ uint32_t lh[4096];
  __shared__ uint32_t sc[256];
  __shared__ int lastFlag;
  for (int i = threadIdx.x; i < 4096; i += 256) lh[i] = 0;
  __syncthreads();
  const uint32_t target = (phase == 0) ? state[0] : ((state[0] << 12) | state[2]);
  const int shift = (phase == 0) ? 24 : 12;
  const int stride = gridDim.x * 256;
  for (int i = blockIdx.x*256 + threadIdx.x; i < NPIX/4; i += stride){
    float4 v = R4[i];
    uint32_t k;
    k = fkey(v.x); if ((k >> shift) == target) atomicAdd(&lh[(k >> (shift-12)) & 0xfffu], 1u);
    k = fkey(v.y); if ((k >> shift) == target) atomicAdd(&lh[(k >> (shift-12)) & 0xfffu], 1u);
    k = fkey(v.z); if ((k >> shift) == target) atomicAdd(&lh[(k >> (shift-12)) & 0xfffu], 1u);
    k = fkey(v.w); if ((k >> shift) == target) atomicAdd(&lh[(k >> (shift-12)) & 0xfffu], 1u);
  }
  __syncthreads();
  for (int i = threadIdx.x; i < 4096; i += 256)
    if (lh[i]) atomicAdd(&h[i], lh[i]);
  __syncthreads();
  if (threadIdx.x == 0){
    __threadfence();
    lastFlag = (atomicAdd(ctr, 1u) == (uint32_t)gridDim.x - 1u);
  }
  __syncthreads();
  if (!lastFlag) return;
  __threadfence();
  const int t = threadIdx.x;
  uint32_t vals[16];
  uint32_t lsum = 0;
#pragma unroll
  for (int i = 0; i < 16; i++){ vals[i] = aload(&h[t*16 + i]); lsum += vals[i]; }
  sc[t] = lsum;
  __syncthreads();
  for (int off = 1; off < 256; off <<= 1){
    uint32_t v = (t >= off) ? sc[t-off] : 0u;
    __syncthreads();
    sc[t] += v;
    __syncthreads();
  }
  uint32_t excl = sc[t] - lsum;
  uint32_t rank = (phase == 0) ? state[1] : state[3];
  if (rank >= excl && rank < excl + lsum){
    uint32_t cum = excl;
    for (int i = 0; i < 16; i++){
      if (rank < cum + vals[i]){
        uint32_t bin = (uint32_t)(t*16 + i);
        if (phase == 0){ state[2] = bin; state[3] = rank - cum; }
        else {
          uint32_t key = (state[0] << 24) | (state[2] << 12) | bin;
          uint32_t u = (key & 0x80000000u) ? (key & 0x7fffffffu) : ~key;
          state[4] = u;
        }
        break;
      }
      cum += vals[i];
    }
  }
}

// ---------------------------------------------------------------------------
// Threshold + 7x7 maxpool NMS. Tile 64x64, halo 3.
// ---------------------------------------------------------------------------
#define PT 64
__global__ __launch_bounds__(256) void harris_nms(
    const float* __restrict__ R, const uint32_t* __restrict__ state,
    float* __restrict__ out)
{
  __shared__ float xt[PT+6][76];
  __shared__ float hm[PT+6][68];

  const int tid = threadIdx.x;
  const int C0 = blockIdx.x * PT;
  const int R0 = blockIdx.y * PT;
  const int n  = blockIdx.z;
  const float med = __uint_as_float(state[4]);
  const float* Rb = R + (size_t)n * (size_t)(IMH*IMW);

  for (int u = tid; u < 70*18; u += 256){
    int r  = u / 18, c4 = u % 18;
    int gr = R0 - 3 + r;
    int gc = C0 - 4 + c4*4;
    float4 v;
    if (gr >= 0 && gr < IMH && gc >= 0 && gc + 3 < IMW){
      v = *reinterpret_cast<const float4*>(&Rb[(size_t)gr*IMW + gc]);
      v.x = v.x > med ? v.x : 0.f;
      v.y = v.y > med ? v.y : 0.f;
      v.z = v.z > med ? v.z : 0.f;
      v.w = v.w > med ? v.w : 0.f;
    } else {
      float t0, t1, t2, t3;
      t0 = (gr>=0&&gr<IMH&&gc+0>=0&&gc+0<IMW) ? Rb[(size_t)gr*IMW+gc+0] : -INFINITY;
      t1 = (gr>=0&&gr<IMH&&gc+1>=0&&gc+1<IMW) ? Rb[(size_t)gr*IMW+gc+1] : -INFINITY;
      t2 = (gr>=0&&gr<IMH&&gc+2>=0&&gc+2<IMW) ? Rb[(size_t)gr*IMW+gc+2] : -INFINITY;
      t3 = (gr>=0&&gr<IMH&&gc+3>=0&&gc+3<IMW) ? Rb[(size_t)gr*IMW+gc+3] : -INFINITY;
      v.x = (t0 == -INFINITY) ? t0 : (t0 > med ? t0 : 0.f);
      v.y = (t1 == -INFINITY) ? t1 : (t1 > med ? t1 : 0.f);
      v.z = (t2 == -INFINITY) ? t2 : (t2 > med ? t2 : 0.f);
      v.w = (t3 == -INFINITY) ? t3 : (t3 > med ? t3 : 0.f);
    }
    *reinterpret_cast<float4*>(&xt[r][c4*4]) = v;
  }
  __syncthreads();

  for (int u = tid; u < 70*16; u += 256){
    int r = u / 16, c4 = u % 16;
    float4 t0 = *reinterpret_cast<const float4*>(&xt[r][c4*4]);
    float4 t1 = *reinterpret_cast<const float4*>(&xt[r][c4*4+4]);
    float4 t2 = *reinterpret_cast<const float4*>(&xt[r][c4*4+8]);
    float w[12];
    w[0]=t0.x; w[1]=t0.y; w[2]=t0.z; w[3]=t0.w;
    w[4]=t1.x; w[5]=t1.y; w[6]=t1.z; w[7]=t1.w;
    w[8]=t2.x; w[9]=t2.y; w[10]=t2.z; w[11]=t2.w;
    float o[4];
#pragma unroll
    for (int j = 0; j < 4; j++){
      float m = w[j+1];
#pragma unroll
      for (int k = 2; k <= 7; k++) m = fmaxf(m, w[j+k]);
      o[j] = m;
    }
    *reinterpret_cast<float4*>(&hm[r][c4*4]) = make_float4(o[0],o[1],o[2],o[3]);
  }
  __syncthreads();

  const int c4o = tid & 15;
  const int r0o = (tid >> 4) * 4;
  float4 hv[10];
#pragma unroll
  for (int k = 0; k < 10; k++)
    hv[k] = *reinterpret_cast<const float4*>(&hm[r0o+k][c4o*4]);

  float* ob = out + (size_t)n * (size_t)(IMH*IMW);
#pragma unroll
  for (int i = 0; i < 4; i++){
    float4 y = hv[i];
#pragma unroll
    for (int k = 1; k < 7; k++){
      float4 t = hv[i+k];
      y.x = fmaxf(y.x, t.x); y.y = fmaxf(y.y, t.y);
      y.z = fmaxf(y.z, t.z); y.w = fmaxf(y.w, t.w);
    }
    float4 c = *reinterpret_cast<const float4*>(&xt[r0o+i+3][c4o*4+4]);
    float4 o;
    o.x = (c.x == y.x) ? c.x : 0.f;
    o.y = (c.y == y.y) ? c.y : 0.f;
    o.z = (c.z == y.z) ? c.z : 0.f;
    o.w = (c.w == y.w) ? c.w : 0.f;
    *reinterpret_cast<float4*>(&ob[(size_t)(R0+r0o+i)*IMW + C0 + c4o*4]) = o;
  }
}

// ---------------------------------------------------------------------------
extern "C" void kernel_launch(void* const* d_in, const int* in_sizes, int n_in,
                              void* d_out, int out_size, void* d_ws, size_t ws_size,
                              hipStream_t stream)
{
  (void)in_sizes; (void)n_in; (void)out_size; (void)ws_size;
  const float* x  = (const float*)d_in[0];
  const float* gw = (const float*)d_in[2];
  float* out = (float*)d_out;

  float* R = (float*)d_ws;
  uint32_t* aux   = (uint32_t*)((char*)d_ws + (size_t)NPIX * sizeof(float));
  uint32_t* h8g   = aux;                         // 256*H8REP = 16384
  uint32_t* h12a  = aux + 16384;                 // 4096
  uint32_t* h12b  = aux + 16384 + 4096;          // 4096
  uint32_t* state = aux + 16384 + 4096 + 4096;   // 8
  uint32_t* ctr   = state + 8;                   // 4 (front, 12a, 12b)

  hipMemsetAsync(aux, 0, (16384 + 4096 + 4096 + 8 + 4) * sizeof(uint32_t), stream);

  harris_front<<<dim3(GX, GY, NB), 256, 0, stream>>>(x, gw, R, h8g, state, ctr);

  harris_hist12<<<1024, 256, 0, stream>>>((const float4*)R, h12a, state, ctr+1, 0);
  harris_hist12<<<1024, 256, 0, stream>>>((const float4*)R, h12b, state, ctr+2, 1);

  harris_nms<<<dim3(IMW/PT, IMH/PT, NB), 256, 0, stream>>>(R, state, out);
}

// Round 5
// 342.765 us; speedup vs baseline: 1.7398x; 1.7398x over previous
//
#include <hip/hip_runtime.h>
#include <cstdint>
#include <math.h>

#define IMH 2048
#define IMW 2048
#define NB 4
#define NPIX (NB*IMH*IMW)        // 16777216
#define MEDRANK ((NPIX-1)/2)     // 8388607
#define ALPHA 0.05f

// front tile: 64 wide x 24 tall
#define TW 64
#define TH 24
#define XROWS (TH+10)   // 34
#define XSTR 84
#define HROWS (TH+8)    // 32
#define HSTR 68

__device__ __forceinline__ uint32_t fkey(float f){
  uint32_t u = __float_as_uint(f);
  return (u & 0x80000000u) ? ~u : (u | 0x80000000u);
}
__device__ __forceinline__ uint32_t aload(const uint32_t* p){
  return __hip_atomic_load(p, __ATOMIC_RELAXED, __HIP_MEMORY_SCOPE_AGENT);
}
__device__ __forceinline__ float ldz(const float* __restrict__ p, int r, int c){
  return (r >= 0 && r < IMH && c >= 0 && c < IMW) ? p[(size_t)r*IMW + c] : 0.f;
}

// ---------------------------------------------------------------------------
// Fused Sobel(separable) -> products -> 9x9 Gaussian -> Harris R.
// LDS: xs 34x84 (11.4KB) + hs 3x32x68 (26.1KB) = 37.5KB -> 4 blocks/CU.
// No VGPR-capping launch_bounds (R3 lesson: (256,4) forced 64 VGPR -> spill).
// No fused histogram (R4 lesson: low-replica LDS atomics serialize 16-32x on
// hot exponent bins -> +300us).
// ---------------------------------------------------------------------------
__global__ __launch_bounds__(256) void harris_front(
    const float* __restrict__ x, const float* __restrict__ gauss_w,
    float* __restrict__ R)
{
  __shared__ float xs[XROWS][XSTR];
  __shared__ float hs[3][HROWS][HSTR];

  const int tid = threadIdx.x;
  const int C0 = blockIdx.x * TW;
  const int R0 = blockIdx.y * TH;
  const int n  = blockIdx.z;
  const float* xb = x + (size_t)n * (size_t)(IMH*IMW);

  float ga[9];
  {
    float a4 = sqrtf(gauss_w[4*9+4]);
#pragma unroll
    for (int i = 0; i < 9; i++) ga[i] = gauss_w[4*9+i] / a4;
  }

  // ---- load x tile: rows R0-5..R0+28 (34), cols C0-8..C0+71 (80) ----
  for (int u = tid; u < XROWS*20; u += 256){
    int r = u / 20, c4 = u % 20;
    int gr = R0 - 5 + r;
    int gc = C0 - 8 + c4*4;
    float4 v;
    if (gr >= 0 && gr < IMH && gc >= 0 && gc + 3 < IMW){
      v = *reinterpret_cast<const float4*>(&xb[(size_t)gr*IMW + gc]);
    } else {
      v.x = ldz(xb, gr, gc+0); v.y = ldz(xb, gr, gc+1);
      v.z = ldz(xb, gr, gc+2); v.w = ldz(xb, gr, gc+3);
    }
    *reinterpret_cast<float4*>(&xs[r][c4*4]) = v;
  }
  __syncthreads();

  // ---- horizontal: Sobel + products + h-gauss, 1 item/thread ----
  {
    const int hr = tid >> 3;            // hs row 0..31
    const int oc = (tid & 7) * 8;       // output col group (8 cols)
    const int gr = R0 - 4 + hr;         // product row
    const bool rowv = ((unsigned)gr < (unsigned)IMH);

    float ix[16], iy[16];
    {
      float sv[24], dv[24];
#pragma unroll
      for (int m = 0; m < 6; m++){
        float4 a = *reinterpret_cast<const float4*>(&xs[hr  ][oc + m*4]);
        float4 b = *reinterpret_cast<const float4*>(&xs[hr+1][oc + m*4]);
        float4 c = *reinterpret_cast<const float4*>(&xs[hr+2][oc + m*4]);
        sv[m*4+0] = fmaf(2.f, b.x, a.x + c.x);  dv[m*4+0] = c.x - a.x;
        sv[m*4+1] = fmaf(2.f, b.y, a.y + c.y);  dv[m*4+1] = c.y - a.y;
        sv[m*4+2] = fmaf(2.f, b.z, a.z + c.z);  dv[m*4+2] = c.z - a.z;
        sv[m*4+3] = fmaf(2.f, b.w, a.w + c.w);  dv[m*4+3] = c.w - a.w;
      }
#pragma unroll
      for (int j = 0; j < 16; j++){
        float vx = sv[j+5] - sv[j+3];
        float vy = dv[j+3] + fmaf(2.f, dv[j+4], dv[j+5]);
        int gc = C0 + oc - 4 + j;
        bool vld = rowv && ((unsigned)gc < (unsigned)IMW);
        ix[j] = vld ? vx : 0.f;
        iy[j] = vld ? vy : 0.f;
      }
    }
#pragma unroll
    for (int p = 0; p < 3; p++){
      float pr[16];
#pragma unroll
      for (int j = 0; j < 16; j++)
        pr[j] = (p == 0) ? ix[j]*ix[j] : (p == 1) ? iy[j]*iy[j] : ix[j]*iy[j];
      float o[8];
#pragma unroll
      for (int t2 = 0; t2 < 8; t2++){
        float s = 0.f;
#pragma unroll
        for (int k = 0; k < 9; k++) s = fmaf(ga[k], pr[t2+k], s);
        o[t2] = s;
      }
      *reinterpret_cast<float4*>(&hs[p][hr][oc])   = make_float4(o[0],o[1],o[2],o[3]);
      *reinterpret_cast<float4*>(&hs[p][hr][oc+4]) = make_float4(o[4],o[5],o[6],o[7]);
    }
  }
  __syncthreads();

  // ---- vertical gauss + Harris + R write, 2 rows x 4 cols, threads 0..191 --
  if (tid < 192){
    const int c4o = tid & 15;
    const int r0o = (tid >> 4) * 2;     // 0..22
    float4 sA[3], sB[3];
#pragma unroll
    for (int p = 0; p < 3; p++){
      float4 a0 = make_float4(0,0,0,0), a1 = make_float4(0,0,0,0);
#pragma unroll
      for (int k = 0; k < 10; k++){
        float4 hv = *reinterpret_cast<const float4*>(&hs[p][r0o+k][c4o*4]);
        if (k < 9){
          a0.x = fmaf(ga[k], hv.x, a0.x); a0.y = fmaf(ga[k], hv.y, a0.y);
          a0.z = fmaf(ga[k], hv.z, a0.z); a0.w = fmaf(ga[k], hv.w, a0.w);
        }
        if (k >= 1){
          a1.x = fmaf(ga[k-1], hv.x, a1.x); a1.y = fmaf(ga[k-1], hv.y, a1.y);
          a1.z = fmaf(ga[k-1], hv.z, a1.z); a1.w = fmaf(ga[k-1], hv.w, a1.w);
        }
      }
      sA[p] = a0; sB[p] = a1;
    }
    float* Rb = R + (size_t)n * (size_t)(IMH*IMW);
    float4 o0, o1;
    float s0, s1, s2, det, tr;
    s0=sA[0].x; s1=sA[1].x; s2=sA[2].x; det=s0*s1-s2*s2; tr=s0+s1; o0.x=det-ALPHA*tr*tr;
    s0=sA[0].y; s1=sA[1].y; s2=sA[2].y; det=s0*s1-s2*s2; tr=s0+s1; o0.y=det-ALPHA*tr*tr;
    s0=sA[0].z; s1=sA[1].z; s2=sA[2].z; det=s0*s1-s2*s2; tr=s0+s1; o0.z=det-ALPHA*tr*tr;
    s0=sA[0].w; s1=sA[1].w; s2=sA[2].w; det=s0*s1-s2*s2; tr=s0+s1; o0.w=det-ALPHA*tr*tr;
    s0=sB[0].x; s1=sB[1].x; s2=sB[2].x; det=s0*s1-s2*s2; tr=s0+s1; o1.x=det-ALPHA*tr*tr;
    s0=sB[0].y; s1=sB[1].y; s2=sB[2].y; det=s0*s1-s2*s2; tr=s0+s1; o1.y=det-ALPHA*tr*tr;
    s0=sB[0].z; s1=sB[1].z; s2=sB[2].z; det=s0*s1-s2*s2; tr=s0+s1; o1.z=det-ALPHA*tr*tr;
    s0=sB[0].w; s1=sB[1].w; s2=sB[2].w; det=s0*s1-s2*s2; tr=s0+s1; o1.w=det-ALPHA*tr*tr;

    const int orow = R0 + r0o;
    const int ocol = C0 + c4o*4;
    if (orow < IMH)
      *reinterpret_cast<float4*>(&Rb[(size_t)orow*IMW + ocol]) = o0;
    if (orow + 1 < IMH)
      *reinterpret_cast<float4*>(&Rb[(size_t)(orow+1)*IMW + ocol]) = o1;
  }
}

// ---------------------------------------------------------------------------
// Median pass 1: 8-bit histogram, 32 LDS replicas (copy = lane&31 -> bank ==
// lane, same-address only 2-way = free), tail-block select.
// ---------------------------------------------------------------------------
#define HREP 32
__global__ __launch_bounds__(256) void harris_hist8(
    const float4* __restrict__ R4, uint32_t* __restrict__ h8,
    uint32_t* __restrict__ state, uint32_t* __restrict__ ctr)
{
  __shared__ uint32_t lh[256*HREP];
  __shared__ uint32_t sc[256];
  __shared__ int lastFlag;
  for (int i = threadIdx.x; i < 256*HREP; i += 256) lh[i] = 0;
  __syncthreads();
  const int copy = threadIdx.x & (HREP-1);
  const int stride = gridDim.x * 256;
  for (int i = blockIdx.x*256 + threadIdx.x; i < NPIX/4; i += stride){
    float4 v = R4[i];
    atomicAdd(&lh[(fkey(v.x) >> 24)*HREP + copy], 1u);
    atomicAdd(&lh[(fkey(v.y) >> 24)*HREP + copy], 1u);
    atomicAdd(&lh[(fkey(v.z) >> 24)*HREP + copy], 1u);
    atomicAdd(&lh[(fkey(v.w) >> 24)*HREP + copy], 1u);
  }
  __syncthreads();
  {
    const int t = threadIdx.x;
    uint32_t s = 0;
#pragma unroll
    for (int i = 0; i < HREP; i++) s += lh[t*HREP + ((t + i) & (HREP-1))];
    if (s) atomicAdd(&h8[t], s);
  }
  __syncthreads();
  if (threadIdx.x == 0){
    __threadfence();
    lastFlag = (atomicAdd(ctr, 1u) == (uint32_t)gridDim.x - 1u);
  }
  __syncthreads();
  if (!lastFlag) return;
  __threadfence();
  const int t = threadIdx.x;
  uint32_t cnt = aload(&h8[t]);
  sc[t] = cnt;
  __syncthreads();
  for (int off = 1; off < 256; off <<= 1){
    uint32_t v = (t >= off) ? sc[t-off] : 0u;
    __syncthreads();
    sc[t] += v;
    __syncthreads();
  }
  uint32_t excl = sc[t] - cnt;
  if ((uint32_t)MEDRANK >= excl && (uint32_t)MEDRANK < excl + cnt){
    state[0] = (uint32_t)t;
    state[1] = (uint32_t)MEDRANK - excl;
  }
}

// ---------------------------------------------------------------------------
// Median passes 2/3: 12-bit refinement with tail-block select.
// ---------------------------------------------------------------------------
__global__ __launch_bounds__(256) void harris_hist12(
    const float4* __restrict__ R4, uint32_t* __restrict__ h,
    uint32_t* __restrict__ state, uint32_t* __restrict__ ctr, int phase)
{
  __shared__ uint32_t lh[4096];
  __shared__ uint32_t sc[256];
  __shared__ int lastFlag;
  for (int i = threadIdx.x; i < 4096; i += 256) lh[i] = 0;
  __syncthreads();
  const uint32_t target = (phase == 0) ? state[0] : ((state[0] << 12) | state[2]);
  const int shift = (phase == 0) ? 24 : 12;
  const int stride = gridDim.x * 256;
  for (int i = blockIdx.x*256 + threadIdx.x; i < NPIX/4; i += stride){
    float4 v = R4[i];
    uint32_t k;
    k = fkey(v.x); if ((k >> shift) == target) atomicAdd(&lh[(k >> (shift-12)) & 0xfffu], 1u);
    k = fkey(v.y); if ((k >> shift) == target) atomicAdd(&lh[(k >> (shift-12)) & 0xfffu], 1u);
    k = fkey(v.z); if ((k >> shift) == target) atomicAdd(&lh[(k >> (shift-12)) & 0xfffu], 1u);
    k = fkey(v.w); if ((k >> shift) == target) atomicAdd(&lh[(k >> (shift-12)) & 0xfffu], 1u);
  }
  __syncthreads();
  for (int i = threadIdx.x; i < 4096; i += 256)
    if (lh[i]) atomicAdd(&h[i], lh[i]);
  __syncthreads();
  if (threadIdx.x == 0){
    __threadfence();
    lastFlag = (atomicAdd(ctr, 1u) == (uint32_t)gridDim.x - 1u);
  }
  __syncthreads();
  if (!lastFlag) return;
  __threadfence();
  const int t = threadIdx.x;
  uint32_t vals[16];
  uint32_t lsum = 0;
#pragma unroll
  for (int i = 0; i < 16; i++){ vals[i] = aload(&h[t*16 + i]); lsum += vals[i]; }
  sc[t] = lsum;
  __syncthreads();
  for (int off = 1; off < 256; off <<= 1){
    uint32_t v = (t >= off) ? sc[t-off] : 0u;
    __syncthreads();
    sc[t] += v;
    __syncthreads();
  }
  uint32_t excl = sc[t] - lsum;
  uint32_t rank = (phase == 0) ? state[1] : state[3];
  if (rank >= excl && rank < excl + lsum){
    uint32_t cum = excl;
    for (int i = 0; i < 16; i++){
      if (rank < cum + vals[i]){
        uint32_t bin = (uint32_t)(t*16 + i);
        if (phase == 0){ state[2] = bin; state[3] = rank - cum; }
        else {
          uint32_t key = (state[0] << 24) | (state[2] << 12) | bin;
          uint32_t u = (key & 0x80000000u) ? (key & 0x7fffffffu) : ~key;
          state[4] = u;
        }
        break;
      }
      cum += vals[i];
    }
  }
}

// ---------------------------------------------------------------------------
// Threshold + 7x7 maxpool NMS. Tile 64x64, halo 3.
// ---------------------------------------------------------------------------
#define PT 64
__global__ __launch_bounds__(256) void harris_nms(
    const float* __restrict__ R, const uint32_t* __restrict__ state,
    float* __restrict__ out)
{
  __shared__ float xt[PT+6][76];
  __shared__ float hm[PT+6][68];

  const int tid = threadIdx.x;
  const int C0 = blockIdx.x * PT;
  const int R0 = blockIdx.y * PT;
  const int n  = blockIdx.z;
  const float med = __uint_as_float(state[4]);
  const float* Rb = R + (size_t)n * (size_t)(IMH*IMW);

  for (int u = tid; u < 70*18; u += 256){
    int r  = u / 18, c4 = u % 18;
    int gr = R0 - 3 + r;
    int gc = C0 - 4 + c4*4;
    float4 v;
    if (gr >= 0 && gr < IMH && gc >= 0 && gc + 3 < IMW){
      v = *reinterpret_cast<const float4*>(&Rb[(size_t)gr*IMW + gc]);
      v.x = v.x > med ? v.x : 0.f;
      v.y = v.y > med ? v.y : 0.f;
      v.z = v.z > med ? v.z : 0.f;
      v.w = v.w > med ? v.w : 0.f;
    } else {
      float t0, t1, t2, t3;
      t0 = (gr>=0&&gr<IMH&&gc+0>=0&&gc+0<IMW) ? Rb[(size_t)gr*IMW+gc+0] : -INFINITY;
      t1 = (gr>=0&&gr<IMH&&gc+1>=0&&gc+1<IMW) ? Rb[(size_t)gr*IMW+gc+1] : -INFINITY;
      t2 = (gr>=0&&gr<IMH&&gc+2>=0&&gc+2<IMW) ? Rb[(size_t)gr*IMW+gc+2] : -INFINITY;
      t3 = (gr>=0&&gr<IMH&&gc+3>=0&&gc+3<IMW) ? Rb[(size_t)gr*IMW+gc+3] : -INFINITY;
      v.x = (t0 == -INFINITY) ? t0 : (t0 > med ? t0 : 0.f);
      v.y = (t1 == -INFINITY) ? t1 : (t1 > med ? t1 : 0.f);
      v.z = (t2 == -INFINITY) ? t2 : (t2 > med ? t2 : 0.f);
      v.w = (t3 == -INFINITY) ? t3 : (t3 > med ? t3 : 0.f);
    }
    *reinterpret_cast<float4*>(&xt[r][c4*4]) = v;
  }
  __syncthreads();

  for (int u = tid; u < 70*16; u += 256){
    int r = u / 16, c4 = u % 16;
    float4 t0 = *reinterpret_cast<const float4*>(&xt[r][c4*4]);
    float4 t1 = *reinterpret_cast<const float4*>(&xt[r][c4*4+4]);
    float4 t2 = *reinterpret_cast<const float4*>(&xt[r][c4*4+8]);
    float w[12];
    w[0]=t0.x; w[1]=t0.y; w[2]=t0.z; w[3]=t0.w;
    w[4]=t1.x; w[5]=t1.y; w[6]=t1.z; w[7]=t1.w;
    w[8]=t2.x; w[9]=t2.y; w[10]=t2.z; w[11]=t2.w;
    float o[4];
#pragma unroll
    for (int j = 0; j < 4; j++){
      float m = w[j+1];
#pragma unroll
      for (int k = 2; k <= 7; k++) m = fmaxf(m, w[j+k]);
      o[j] = m;
    }
    *reinterpret_cast<float4*>(&hm[r][c4*4]) = make_float4(o[0],o[1],o[2],o[3]);
  }
  __syncthreads();

  const int c4o = tid & 15;
  const int r0o = (tid >> 4) * 4;
  float4 hv[10];
#pragma unroll
  for (int k = 0; k < 10; k++)
    hv[k] = *reinterpret_cast<const float4*>(&hm[r0o+k][c4o*4]);

  float* ob = out + (size_t)n * (size_t)(IMH*IMW);
#pragma unroll
  for (int i = 0; i < 4; i++){
    float4 y = hv[i];
#pragma unroll
    for (int k = 1; k < 7; k++){
      float4 t = hv[i+k];
      y.x = fmaxf(y.x, t.x); y.y = fmaxf(y.y, t.y);
      y.z = fmaxf(y.z, t.z); y.w = fmaxf(y.w, t.w);
    }
    float4 c = *reinterpret_cast<const float4*>(&xt[r0o+i+3][c4o*4+4]);
    float4 o;
    o.x = (c.x == y.x) ? c.x : 0.f;
    o.y = (c.y == y.y) ? c.y : 0.f;
    o.z = (c.z == y.z) ? c.z : 0.f;
    o.w = (c.w == y.w) ? c.w : 0.f;
    *reinterpret_cast<float4*>(&ob[(size_t)(R0+r0o+i)*IMW + C0 + c4o*4]) = o;
  }
}

// ---------------------------------------------------------------------------
extern "C" void kernel_launch(void* const* d_in, const int* in_sizes, int n_in,
                              void* d_out, int out_size, void* d_ws, size_t ws_size,
                              hipStream_t stream)
{
  (void)in_sizes; (void)n_in; (void)out_size; (void)ws_size;
  const float* x  = (const float*)d_in[0];
  const float* gw = (const float*)d_in[2];
  float* out = (float*)d_out;

  float* R = (float*)d_ws;
  uint32_t* aux   = (uint32_t*)((char*)d_ws + (size_t)NPIX * sizeof(float));
  uint32_t* h8    = aux;                        // 256
  uint32_t* h12a  = aux + 256;                  // 4096
  uint32_t* h12b  = aux + 256 + 4096;           // 4096
  uint32_t* state = aux + 256 + 4096 + 4096;    // 8
  uint32_t* ctr   = state + 8;                  // 3

  hipMemsetAsync(aux, 0, (256 + 4096 + 4096 + 8 + 3) * sizeof(uint32_t), stream);

  harris_front<<<dim3(IMW/TW, (IMH + TH - 1)/TH, NB), 256, 0, stream>>>(x, gw, R);

  harris_hist8 <<<1024, 256, 0, stream>>>((const float4*)R, h8, state, ctr);
  harris_hist12<<<1024, 256, 0, stream>>>((const float4*)R, h12a, state, ctr+1, 0);
  harris_hist12<<<1024, 256, 0, stream>>>((const float4*)R, h12b, state, ctr+2, 1);

  harris_nms<<<dim3(IMW/PT, IMH/PT, NB), 256, 0, stream>>>(R, state, out);
}